// Round 3
// baseline (26.932 us; speedup 1.0000x reference)
//
#include <hip/hip_runtime.h>

#define DD 6
#define SDIM 17
#define CAPF 20.0f
#define BIGF 1e30f
#define ROWS 256                 // rows per block == blockDim.x
#define WSLAB 1088               // floats per wave slab (64 rows * 17)

__global__ __launch_bounds__(256) void proj_wl1_kernel(
    const float* __restrict__ x, const float* __restrict__ s,
    float* __restrict__ out, int B)
{
    __shared__ float lds[4 * WSLAB];   // 17408 B; one 4352-B slab per wave

    const int tid  = threadIdx.x;
    const int wv   = tid >> 6;
    const int lane = tid & 63;
    const size_t row0  = (size_t)blockIdx.x * ROWS;
    const size_t wrow0 = row0 + (size_t)wv * 64;   // this wave's first row
    const bool full = (row0 + ROWS) <= (size_t)B;

    float* lsw = lds + wv * WSLAB;
    float q[DD], w[DD];

    if (full) {
        // ---- stage this wave's s-slab (64 rows x 17 f = 272 float4), coalesced ----
        const float4* gs  = reinterpret_cast<const float4*>(s + wrow0 * SDIM);
        float4* lsw4      = reinterpret_cast<float4*>(lsw);
#pragma unroll
        for (int it = 0; it < 4; ++it)
            lsw4[it * 64 + lane] = gs[it * 64 + lane];
        if (lane < 16)
            lsw4[256 + lane] = gs[256 + lane];

        // ---- direct x loads (float2; 24B rows fully cover cache lines) ----
        const float* xp = x + (wrow0 + lane) * DD;
        float2 q01 = *reinterpret_cast<const float2*>(xp + 0);
        float2 q23 = *reinterpret_cast<const float2*>(xp + 2);
        float2 q45 = *reinterpret_cast<const float2*>(xp + 4);
        q[0] = q01.x; q[1] = q01.y; q[2] = q23.x;
        q[3] = q23.y; q[4] = q45.x; q[5] = q45.y;

        // wave-local LDS visibility: DS is in-order per wave; drain lgkm
        asm volatile("s_waitcnt lgkmcnt(0)" ::: "memory");
#pragma unroll
        for (int i = 0; i < DD; ++i)
            w[i] = fabsf(lsw[lane * SDIM + 11 + i]);   // stride 17 (odd) = conflict-free
    } else {
        size_t row = wrow0 + lane;
        bool ok = row < (size_t)B;
        const float* xp = x + row * DD;
        const float* sp = s + row * SDIM + 11;
#pragma unroll
        for (int i = 0; i < DD; ++i) q[i] = ok ? xp[i] : 0.f;
#pragma unroll
        for (int i = 0; i < DD; ++i) w[i] = ok ? fabsf(sp[i]) : 0.f;
    }

    // ---- closed-form weighted-L1 projection (exact reference semantics) ----
    float a[DD], r[DD], wq[DD], w2[DD];
    float total = 0.f;
#pragma unroll
    for (int i = 0; i < DD; ++i) {
        a[i]  = fabsf(q[i]);
        wq[i] = w[i] * a[i];
        w2[i] = w[i] * w[i];
        total += wq[i];
        r[i]  = (w[i] > 0.f) ? (a[i] / w[i]) : BIGF;
    }

    // sort (r, wq, w2) descending by r — 15-cswap unrolled bubble network
#pragma unroll
    for (int i = 0; i < DD - 1; ++i) {
#pragma unroll
        for (int j = 0; j < DD - 1 - i; ++j) {
            bool sw = r[j] < r[j + 1];
            float t0 = r[j], t1 = wq[j], t2 = w2[j];
            r[j]  = sw ? r[j + 1]  : r[j];
            wq[j] = sw ? wq[j + 1] : wq[j];
            w2[j] = sw ? w2[j + 1] : w2[j];
            r[j + 1]  = sw ? t0 : r[j + 1];
            wq[j + 1] = sw ? t1 : wq[j + 1];
            w2[j + 1] = sw ? t2 : w2[j + 1];
        }
    }

    float cwq = 0.f, cw2 = 0.f;
    float lamk[DD];
    int m = 0;
#pragma unroll
    for (int k = 0; k < DD; ++k) {
        cwq += wq[k];
        cw2 += w2[k];
        float safe = (cw2 > 0.f) ? cw2 : 1.f;
        lamk[k] = (cwq - CAPF) / safe;
        bool valid = (r[k] > lamk[k]) && (cw2 > 0.f);
        m += valid ? 1 : 0;
    }
    int ks = m - 1;
    if (ks < 0) ks = 0;
    float lam = lamk[0];
#pragma unroll
    for (int k = 1; k < DD; ++k) lam = (ks == k) ? lamk[k] : lam;
    lam = (total > CAPF) ? fmaxf(lam, 0.f) : 0.f;

    float o[DD];
#pragma unroll
    for (int i = 0; i < DD; ++i) {
        float mag = fmaxf(a[i] - lam * w[i], 0.f);
        float sgn = (q[i] > 0.f) ? 1.f : ((q[i] < 0.f) ? -1.f : 0.f);
        o[i] = sgn * mag;
    }

    if (full) {
        // ---- reuse the wave slab to assemble out, then pure float4 stores ----
        // Safe without barriers: same-wave DS ops are in-order (reads of w done above).
#pragma unroll
        for (int i = 0; i < DD; ++i)
            lsw[lane * DD + i] = o[i];
        asm volatile("s_waitcnt lgkmcnt(0)" ::: "memory");

        float4* go = reinterpret_cast<float4*>(out + wrow0 * DD);
        const float4* lsw4 = reinterpret_cast<const float4*>(lsw);
        go[lane] = lsw4[lane];
        if (lane < 32)
            go[64 + lane] = lsw4[64 + lane];
    } else {
        size_t row = wrow0 + lane;
        if (row < (size_t)B) {
            float* op = out + row * DD;
#pragma unroll
            for (int i = 0; i < DD; ++i) op[i] = o[i];
        }
    }
}

extern "C" void kernel_launch(void* const* d_in, const int* in_sizes, int n_in,
                              void* d_out, int out_size, void* d_ws, size_t ws_size,
                              hipStream_t stream)
{
    const float* x = (const float*)d_in[0];
    const float* s = (const float*)d_in[1];
    float* out = (float*)d_out;
    int B = in_sizes[0] / DD;

    const int block = ROWS;
    int grid = (B + block - 1) / block;
    proj_wl1_kernel<<<grid, block, 0, stream>>>(x, s, out, B);
}